// Round 3
// baseline (389.658 us; speedup 1.0000x reference)
//
#include <hip/hip_runtime.h>
#include <hip/hip_bf16.h>
#include <math.h>

#define BSZ 256
#define MAX_LEN 1024
#define DD 256      // D
#define DA 128      // D_ATTN

typedef short short8 __attribute__((ext_vector_type(8)));
typedef short short4v __attribute__((ext_vector_type(4)));
typedef float floatx4 __attribute__((ext_vector_type(4)));

__device__ __forceinline__ short f2bf(float f) {
    union { float f; unsigned u; } x;
    x.f = f;
    // round-to-nearest-even fp32 -> bf16
    unsigned r = (x.u + 0x7FFFu + ((x.u >> 16) & 1u)) >> 16;
    return (short)r;
}

__device__ __forceinline__ float fast_exp2(float x) {
#if __has_builtin(__builtin_amdgcn_exp2f)
    return __builtin_amdgcn_exp2f(x);
#else
    return exp2f(x);
#endif
}
__device__ __forceinline__ float fast_rcp(float x) {
#if __has_builtin(__builtin_amdgcn_rcpf)
    return __builtin_amdgcn_rcpf(x);
#else
    return 1.0f / x;
#endif
}
// tanh(x) = 1 - 2/(exp2(x*2*log2e) + 1); exact saturation at +-inf.
__device__ __forceinline__ float fast_tanh(float x) {
    float e = fast_exp2(x * 2.8853900817779268f);
    return 1.0f - 2.0f * fast_rcp(e + 1.0f);
}

// Kernel 1: v[b, j] = sum_a tanh( (emb_q[b,:] . w_f[j,a,:]) + b_f[j,a] ) * w_h[a]
// One block per j. w_f[j] staged to LDS as bf16 in two 64-a halves (XOR-swizzled
// 16B chunks). Full-depth MLP: BOTH halves' global loads issued at the top (32
// dwordx4/thread in flight); half-0 LDS writes drain the first 16 via vmcnt while
// half-1 stays in flight under the half-0 MFMA+tanh phase (T14 write-late).
__global__ __launch_bounds__(256, 1) void v_kernel(
    const float* __restrict__ emb_q,   // [BSZ, DD]
    const float* __restrict__ w_f,     // [DD, DA, DD]  (j, a, k)
    const float* __restrict__ b_f,     // [DD, DA]
    const float* __restrict__ w_h,     // [DA]
    float* __restrict__ v)             // [BSZ, DD]  (b, j)
{
    __shared__ short lds_b[2][64 * DD];   // 2 x 32768 B, bf16, chunk-swizzled
    const int j   = blockIdx.x;
    const int tid = threadIdx.x;
    const float* wj = w_f + (size_t)j * (DA * DD);

    // ---- issue global loads for BOTH a-halves up front (max MLP) ----
    float4 tmp0[16], tmp1[16];
    #pragma unroll
    for (int it = 0; it < 16; ++it)
        tmp0[it] = ((const float4*)wj)[tid + it * 256];
    #pragma unroll
    for (int it = 0; it < 16; ++it)
        tmp1[it] = ((const float4*)(wj + 64 * DD))[tid + it * 256];

    const int lane = tid & 63;
    const int wave = tid >> 6;
    const int l15  = lane & 15;
    const int quad = lane >> 4;

    // ---- A fragments (emb_q) — L2/LLC-resident after first blocks ----
    // A[m = l15][k = quad*8 + jj], 8 consecutive fp32 -> bf16
    short8 afrag[4][8];
    #pragma unroll
    for (int t = 0; t < 4; ++t) {
        const int b0 = (wave * 4 + t) * 16;
        const float* arow = emb_q + (size_t)(b0 + l15) * DD + quad * 8;
        #pragma unroll
        for (int ks = 0; ks < 8; ++ks) {
            float4 v0 = ((const float4*)(arow + ks * 32))[0];
            float4 v1 = ((const float4*)(arow + ks * 32))[1];
            short8 f;
            f[0]=f2bf(v0.x); f[1]=f2bf(v0.y); f[2]=f2bf(v0.z); f[3]=f2bf(v0.w);
            f[4]=f2bf(v1.x); f[5]=f2bf(v1.y); f[6]=f2bf(v1.z); f[7]=f2bf(v1.w);
            afrag[t][ks] = f;
        }
    }

    // ---- convert + write half 0 into LDS (waits only on the first 16 loads) ----
    #pragma unroll
    for (int it = 0; it < 16; ++it) {
        int f4 = tid + it * 256;        // float4 index within half, 0..4095
        int al = f4 >> 6;               // local row 0..63 (64 float4 per row)
        int kq = f4 & 63;
        int c    = kq >> 1;             // 16B chunk index, 0..31
        int hf   = kq & 1;
        int sc   = c ^ (al & 31);       // XOR swizzle kills bank conflicts
        short4v s;
        s[0] = f2bf(tmp0[it].x); s[1] = f2bf(tmp0[it].y);
        s[2] = f2bf(tmp0[it].z); s[3] = f2bf(tmp0[it].w);
        *(short4v*)&lds_b[0][al * DD + sc * 8 + hf * 4] = s;
    }
    __syncthreads();

    float p[4][4];
    #pragma unroll
    for (int t = 0; t < 4; ++t) { p[t][0]=0.f; p[t][1]=0.f; p[t][2]=0.f; p[t][3]=0.f; }

    auto computeAt = [&](int at, int h) {
        const int a   = at * 16 + l15;   // this lane's output column (n = a)
        const int al  = a & 63;          // row within the half buffer
        const float bfv = b_f[j * DA + a];
        const float whv = w_h[a];
        floatx4 acc[4];
        #pragma unroll
        for (int t = 0; t < 4; ++t) acc[t] = (floatx4){0.f, 0.f, 0.f, 0.f};
        #pragma unroll
        for (int ks = 0; ks < 8; ++ks) {
            // B[n = l15 (row a)][k = quad*8 + jj] from swizzled LDS
            const int sc = (4 * ks + quad) ^ (al & 31);
            short8 bfrag = *(const short8*)&lds_b[h][al * DD + sc * 8];
            #pragma unroll
            for (int t = 0; t < 4; ++t)
                acc[t] = __builtin_amdgcn_mfma_f32_16x16x32_bf16(afrag[t][ks], bfrag, acc[t], 0, 0, 0);
        }
        // D[row = quad*4 + r][col = l15]: row -> b offset, col -> a
        #pragma unroll
        for (int t = 0; t < 4; ++t)
            #pragma unroll
            for (int r = 0; r < 4; ++r)
                p[t][r] += fast_tanh(acc[t][r] + bfv) * whv;
    };

    #pragma unroll
    for (int at = 0; at < 4; ++at) computeAt(at, 0);

    // ---- convert + write half 1 (loads have been in flight since the top) ----
    #pragma unroll
    for (int it = 0; it < 16; ++it) {
        int f4 = tid + it * 256;
        int al = f4 >> 6;
        int kq = f4 & 63;
        int c    = kq >> 1;
        int hf   = kq & 1;
        int sc   = c ^ (al & 31);
        short4v s;
        s[0] = f2bf(tmp1[it].x); s[1] = f2bf(tmp1[it].y);
        s[2] = f2bf(tmp1[it].z); s[3] = f2bf(tmp1[it].w);
        *(short4v*)&lds_b[1][al * DD + sc * 8 + hf * 4] = s;
    }
    __syncthreads();

    #pragma unroll
    for (int at = 4; at < 8; ++at) computeAt(at, 1);

    // reduce over a (16 lanes within quad), write v[b, j]
    #pragma unroll
    for (int t = 0; t < 4; ++t) {
        #pragma unroll
        for (int r = 0; r < 4; ++r) {
            float s = p[t][r];
            s += __shfl_xor(s, 1);
            s += __shfl_xor(s, 2);
            s += __shfl_xor(s, 4);
            s += __shfl_xor(s, 8);
            if (l15 == 0) {
                const int b = (wave * 4 + t) * 16 + quad * 4 + r;
                v[b * DD + j] = s;
            }
        }
    }
}

// Kernel 2: weight[b, l] = sum_j emb_iseq[b, l, j] * v[b, j]
// One row (1 KiB) per wave64 dwordx4 load; full-wave butterfly reduce.
// emb_iseq is a 268 MB single-use stream -> nontemporal loads, deep unroll.
__global__ __launch_bounds__(256, 8) void w_kernel(
    const float* __restrict__ emb_iseq, // [BSZ, MAX_LEN, DD]
    const float* __restrict__ v,        // [BSZ, DD]
    float* __restrict__ out)            // [BSZ, MAX_LEN]
{
    const int tid  = threadIdx.x;
    const int lane = tid & 63;
    const int wave = tid >> 6;
    const int b    = blockIdx.x >> 3;   // 8 blocks per batch
    const int lc   = blockIdx.x & 7;    // 128-row chunk

    const floatx4 vv = ((const floatx4*)(v + b * DD))[lane];
    const float* base = emb_iseq + ((size_t)b * MAX_LEN + (size_t)lc * 128) * DD;
    float* obase = out + b * MAX_LEN + lc * 128;

    #pragma unroll 8
    for (int it = 0; it < 32; ++it) {
        const int l = wave * 32 + it;
        floatx4 e = __builtin_nontemporal_load((const floatx4*)(base + (size_t)l * DD) + lane);
        float s = e[0] * vv[0] + e[1] * vv[1] + e[2] * vv[2] + e[3] * vv[3];
        s += __shfl_xor(s, 32);
        s += __shfl_xor(s, 16);
        s += __shfl_xor(s, 8);
        s += __shfl_xor(s, 4);
        s += __shfl_xor(s, 2);
        s += __shfl_xor(s, 1);
        if (lane == 0) obase[l] = s;
    }
}

extern "C" void kernel_launch(void* const* d_in, const int* in_sizes, int n_in,
                              void* d_out, int out_size, void* d_ws, size_t ws_size,
                              hipStream_t stream) {
    const float* emb_q    = (const float*)d_in[0];   // [256, 256]
    const float* emb_iseq = (const float*)d_in[1];   // [256, 1024, 256]
    const float* w_f      = (const float*)d_in[2];   // [256, 128, 256]
    const float* b_f      = (const float*)d_in[3];   // [256, 128]
    const float* w_h      = (const float*)d_in[4];   // [128, 1]
    float* out = (float*)d_out;                      // [256, 1024]
    float* v   = (float*)d_ws;                       // [256, 256] scratch (256 KB)

    v_kernel<<<256, 256, 0, stream>>>(emb_q, w_f, b_f, w_h, v);
    w_kernel<<<2048, 256, 0, stream>>>(emb_iseq, v, out);
}

// Round 4
// 379.270 us; speedup vs baseline: 1.0274x; 1.0274x over previous
//
#include <hip/hip_runtime.h>
#include <hip/hip_bf16.h>
#include <math.h>

#define BSZ 256
#define MAX_LEN 1024
#define DD 256      // D
#define DA 128      // D_ATTN

typedef short short8 __attribute__((ext_vector_type(8)));
typedef short short4v __attribute__((ext_vector_type(4)));
typedef float floatx4 __attribute__((ext_vector_type(4)));

__device__ __forceinline__ short f2bf(float f) {
    union { float f; unsigned u; } x;
    x.f = f;
    // round-to-nearest-even fp32 -> bf16
    unsigned r = (x.u + 0x7FFFu + ((x.u >> 16) & 1u)) >> 16;
    return (short)r;
}

__device__ __forceinline__ float fast_exp2(float x) {
#if __has_builtin(__builtin_amdgcn_exp2f)
    return __builtin_amdgcn_exp2f(x);
#else
    return exp2f(x);
#endif
}
__device__ __forceinline__ float fast_rcp(float x) {
#if __has_builtin(__builtin_amdgcn_rcpf)
    return __builtin_amdgcn_rcpf(x);
#else
    return 1.0f / x;
#endif
}
// tanh(x) = 1 - 2/(exp2(x*2*log2e) + 1); exact saturation at +-inf.
__device__ __forceinline__ float fast_tanh(float x) {
    float e = fast_exp2(x * 2.8853900817779268f);
    return 1.0f - 2.0f * fast_rcp(e + 1.0f);
}

// Kernel 1: v[b, j] = sum_a tanh( (emb_q[b,:] . w_f[j,a,:]) + b_f[j,a] ) * w_h[a]
// One block per j. w_f[j] staged to LDS as bf16 in two 64-a halves (XOR-swizzled
// 16B chunks). T14 pipeline: issue half-1 global loads, compute half-0 MFMAs under
// their latency, then ds_write + barrier. MFMA 16x16x32 bf16: m=b, n=a, k contraction.
// NOTE (round 3 lesson): do NOT issue both halves' loads up front — 128 VGPRs of
// tmp + 128 of afrag live at once (~300 total) spills/serializes; half-at-a-time
// (64 VGPR staging window, ~230 peak) measured fastest.
__global__ __launch_bounds__(256, 1) void v_kernel(
    const float* __restrict__ emb_q,   // [BSZ, DD]
    const float* __restrict__ w_f,     // [DD, DA, DD]  (j, a, k)
    const float* __restrict__ b_f,     // [DD, DA]
    const float* __restrict__ w_h,     // [DA]
    float* __restrict__ v)             // [BSZ, DD]  (b, j)
{
    __shared__ short lds_b[2][64 * DD];   // 2 x 32768 B, bf16, chunk-swizzled
    const int j   = blockIdx.x;
    const int tid = threadIdx.x;
    const float* wj = w_f + (size_t)j * (DA * DD);

    // ---- issue global loads for a-half 0 (rows a=0..63) ----
    float4 tmp[16];
    #pragma unroll
    for (int it = 0; it < 16; ++it)
        tmp[it] = ((const float4*)wj)[tid + it * 256];

    const int lane = tid & 63;
    const int wave = tid >> 6;
    const int l15  = lane & 15;
    const int quad = lane >> 4;

    // ---- A fragments (emb_q) — loads overlap the in-flight w_f half-0 loads ----
    // A[m = l15][k = quad*8 + jj], 8 consecutive fp32 -> bf16
    short8 afrag[4][8];
    #pragma unroll
    for (int t = 0; t < 4; ++t) {
        const int b0 = (wave * 4 + t) * 16;
        const float* arow = emb_q + (size_t)(b0 + l15) * DD + quad * 8;
        #pragma unroll
        for (int ks = 0; ks < 8; ++ks) {
            float4 v0 = ((const float4*)(arow + ks * 32))[0];
            float4 v1 = ((const float4*)(arow + ks * 32))[1];
            short8 f;
            f[0]=f2bf(v0.x); f[1]=f2bf(v0.y); f[2]=f2bf(v0.z); f[3]=f2bf(v0.w);
            f[4]=f2bf(v1.x); f[5]=f2bf(v1.y); f[6]=f2bf(v1.z); f[7]=f2bf(v1.w);
            afrag[t][ks] = f;
        }
    }

    // ---- convert + write half 0 into LDS ----
    #pragma unroll
    for (int it = 0; it < 16; ++it) {
        int f4 = tid + it * 256;        // float4 index within half, 0..4095
        int al = f4 >> 6;               // local row 0..63 (64 float4 per row)
        int kq = f4 & 63;
        int c    = kq >> 1;             // 16B chunk index, 0..31
        int hf   = kq & 1;
        int sc   = c ^ (al & 31);       // XOR swizzle kills bank conflicts
        short4v s;
        s[0] = f2bf(tmp[it].x); s[1] = f2bf(tmp[it].y);
        s[2] = f2bf(tmp[it].z); s[3] = f2bf(tmp[it].w);
        *(short4v*)&lds_b[0][al * DD + sc * 8 + hf * 4] = s;
    }
    __syncthreads();

    // ---- issue global loads for a-half 1 (rows a=64..127); compute hides them ----
    #pragma unroll
    for (int it = 0; it < 16; ++it)
        tmp[it] = ((const float4*)(wj + 64 * DD))[tid + it * 256];

    float p[4][4];
    #pragma unroll
    for (int t = 0; t < 4; ++t) { p[t][0]=0.f; p[t][1]=0.f; p[t][2]=0.f; p[t][3]=0.f; }

    auto computeAt = [&](int at, int h) {
        const int a   = at * 16 + l15;   // this lane's output column (n = a)
        const int al  = a & 63;          // row within the half buffer
        const float bfv = b_f[j * DA + a];
        const float whv = w_h[a];
        floatx4 acc[4];
        #pragma unroll
        for (int t = 0; t < 4; ++t) acc[t] = (floatx4){0.f, 0.f, 0.f, 0.f};
        #pragma unroll
        for (int ks = 0; ks < 8; ++ks) {
            // B[n = l15 (row a)][k = quad*8 + jj] from swizzled LDS
            const int sc = (4 * ks + quad) ^ (al & 31);
            short8 bfrag = *(const short8*)&lds_b[h][al * DD + sc * 8];
            #pragma unroll
            for (int t = 0; t < 4; ++t)
                acc[t] = __builtin_amdgcn_mfma_f32_16x16x32_bf16(afrag[t][ks], bfrag, acc[t], 0, 0, 0);
        }
        // D[row = quad*4 + r][col = l15]: row -> b offset, col -> a
        #pragma unroll
        for (int t = 0; t < 4; ++t)
            #pragma unroll
            for (int r = 0; r < 4; ++r)
                p[t][r] += fast_tanh(acc[t][r] + bfv) * whv;
    };

    #pragma unroll
    for (int at = 0; at < 4; ++at) computeAt(at, 0);

    // ---- convert + write half 1 (loads have been in flight across the compute) ----
    #pragma unroll
    for (int it = 0; it < 16; ++it) {
        int f4 = tid + it * 256;
        int al = f4 >> 6;
        int kq = f4 & 63;
        int c    = kq >> 1;
        int hf   = kq & 1;
        int sc   = c ^ (al & 31);
        short4v s;
        s[0] = f2bf(tmp[it].x); s[1] = f2bf(tmp[it].y);
        s[2] = f2bf(tmp[it].z); s[3] = f2bf(tmp[it].w);
        *(short4v*)&lds_b[1][al * DD + sc * 8 + hf * 4] = s;
    }
    __syncthreads();

    #pragma unroll
    for (int at = 4; at < 8; ++at) computeAt(at, 1);

    // reduce over a (16 lanes within quad), write v[b, j]
    #pragma unroll
    for (int t = 0; t < 4; ++t) {
        #pragma unroll
        for (int r = 0; r < 4; ++r) {
            float s = p[t][r];
            s += __shfl_xor(s, 1);
            s += __shfl_xor(s, 2);
            s += __shfl_xor(s, 4);
            s += __shfl_xor(s, 8);
            if (l15 == 0) {
                const int b = (wave * 4 + t) * 16 + quad * 4 + r;
                v[b * DD + j] = s;
            }
        }
    }
}

// Kernel 2: weight[b, l] = sum_j emb_iseq[b, l, j] * v[b, j]
// One row (1 KiB) per wave64 dwordx4 load; full-wave butterfly reduce.
// emb_iseq is a 268 MB single-use stream -> nontemporal loads.
// NOTE (round 3 lesson): keep unroll 4 — unroll 8 exceeds the 64-VGPR budget
// at __launch_bounds__(256,8) and regressed the stream.
__global__ __launch_bounds__(256, 8) void w_kernel(
    const float* __restrict__ emb_iseq, // [BSZ, MAX_LEN, DD]
    const float* __restrict__ v,        // [BSZ, DD]
    float* __restrict__ out)            // [BSZ, MAX_LEN]
{
    const int tid  = threadIdx.x;
    const int lane = tid & 63;
    const int wave = tid >> 6;
    const int b    = blockIdx.x >> 3;   // 8 blocks per batch
    const int lc   = blockIdx.x & 7;    // 128-row chunk

    const floatx4 vv = ((const floatx4*)(v + b * DD))[lane];
    const float* base = emb_iseq + ((size_t)b * MAX_LEN + (size_t)lc * 128) * DD;
    float* obase = out + b * MAX_LEN + lc * 128;

    #pragma unroll 4
    for (int it = 0; it < 32; ++it) {
        const int l = wave * 32 + it;
        floatx4 e = __builtin_nontemporal_load((const floatx4*)(base + (size_t)l * DD) + lane);
        float s = e[0] * vv[0] + e[1] * vv[1] + e[2] * vv[2] + e[3] * vv[3];
        s += __shfl_xor(s, 32);
        s += __shfl_xor(s, 16);
        s += __shfl_xor(s, 8);
        s += __shfl_xor(s, 4);
        s += __shfl_xor(s, 2);
        s += __shfl_xor(s, 1);
        if (lane == 0) obase[l] = s;
    }
}

extern "C" void kernel_launch(void* const* d_in, const int* in_sizes, int n_in,
                              void* d_out, int out_size, void* d_ws, size_t ws_size,
                              hipStream_t stream) {
    const float* emb_q    = (const float*)d_in[0];   // [256, 256]
    const float* emb_iseq = (const float*)d_in[1];   // [256, 1024, 256]
    const float* w_f      = (const float*)d_in[2];   // [256, 128, 256]
    const float* b_f      = (const float*)d_in[3];   // [256, 128]
    const float* w_h      = (const float*)d_in[4];   // [128, 1]
    float* out = (float*)d_out;                      // [256, 1024]
    float* v   = (float*)d_ws;                       // [256, 256] scratch (256 KB)

    v_kernel<<<256, 256, 0, stream>>>(emb_q, w_f, b_f, w_h, v);
    w_kernel<<<2048, 256, 0, stream>>>(emb_iseq, v, out);
}